// Round 19
// baseline (197.858 us; speedup 1.0000x reference)
//
#include <hip/hip_runtime.h>
#include <hip/hip_bf16.h>
#include <stdint.h>

// SelfBallPointQuery: B=16, C=3, N=2048, RADIUS^2=0.04, MAX_SAMPLES=64.
// R19: PHASE-RESOLVED INSTRUMENTATION (sacrifice round). R16/R18 established
// per-pass ~21us invariant under scalar->packed math (v_pk_*_f32 is 4cyc on
// CDNA4 -- no extra fp32 datapath; spec 157TF has no packed term). The 2x gap
// to the ~10.5us VALU floor is unattributed between test and emit because
// neither phase has ever been individually visible (<40us fill-op cutoff).
// K1 (mask build, 2048x256, 32 waves/CU) rep x8 and K2 (emit, 512x512) rep x8
// so BOTH exceed 40us and return separate counters. asm("":"+v") opaque
// barriers defeat loop-invariant hoisting so each rep recomputes.
// Masks staged in d_out region qg (4096 ints == the qg output region);
// K2 rewrites it with final indices on the copy-out after its rep loop.

#define B_DIM 16
#define N_PTS 2048
#define K_OUT 64
#define R2 0.04f
#define ROWPAD 65
#define REPS 8

typedef float v2f __attribute__((ext_vector_type(2)));

// ---------------- K1: dense mask build ----------------
// grid 2048 = 512 qg x 4 ; 256 thr = 4 waves; wave -> one 128-pt window
__global__ __launch_bounds__(256, 8) void bq_mask_kernel(
    const float* __restrict__ pcs,
    int* __restrict__ out)           // masks: out[qg*4096 + w*64 + lane]
{
    const int bid  = blockIdx.x;
    const int qg   = bid >> 2;
    const int b    = qg >> 5;
    const int g    = qg & 31;
    const int tid  = threadIdx.x;
    const int wave = __builtin_amdgcn_readfirstlane(tid >> 6);
    const int lane = tid & 63;
    const int win  = (bid & 3) * 4 + wave;     // 0..15

    const float* __restrict__ sx = pcs + (size_t)b * 3 * N_PTS;
    const float* __restrict__ sy = sx + N_PTS;
    const float* __restrict__ sz = sy + N_PTS;

    const int qi = g * 64 + lane;
    float nx = -sx[qi], ny = -sy[qi], nz = -sz[qi];

    const int jbase = win * 128;
    int* const mbase = out + (size_t)qg * 4096;

    for (int rep = 0; rep < REPS; ++rep) {
        // opaque: force recompute each rep (values unchanged)
        asm("" : "+v"(nx), "+v"(ny), "+v"(nz));
        #pragma unroll
        for (int i = 0; i < 4; ++i) {          // word w = win*4 + i
            unsigned m = 0;
            #pragma unroll
            for (int k = 31; k >= 0; --k) {    // descending: bit k = point +k
                const int j = jbase + i * 32 + k;   // uniform
                const float dx = sx[j] + nx;   // == sx[j] - qx exactly
                const float dy = sy[j] + ny;
                const float dz = sz[j] + nz;
                const float d2 = __fadd_rn(__fadd_rn(__fmul_rn(dx, dx),
                                                     __fmul_rn(dy, dy)),
                                           __fmul_rn(dz, dz));
                m = m + m + (unsigned)(d2 < R2);
            }
            mbase[(win * 4 + i) * 64 + lane] = (int)m;   // coalesced
        }
    }
}

// ---------------- K2: prefix + emit ----------------
// grid 512 (one per qg); 512 thr = 8 waves; wave v owns words v*8..v*8+7
#define WAVES 8
__global__ __launch_bounds__(512, 4) void bq_emit_kernel(
    int* __restrict__ out)
{
    __shared__ int rows[64 * ROWPAD];
    __shared__ int cntS[WAVES][64];
    __shared__ int qfS[WAVES][64];

    const int qg   = blockIdx.x;
    const int tid  = threadIdx.x;
    const int wave = tid >> 6;
    const int lane = tid & 63;

    int* const reg = out + (size_t)qg * 4096;

    // one-time coalesced mask load into registers
    unsigned mask[8];
    #pragma unroll
    for (int i = 0; i < 8; ++i)
        mask[i] = (unsigned)reg[(wave * 8 + i) * 64 + lane];

    for (int rep = 0; rep < REPS; ++rep) {
        // opaque: force full recompute each rep
        #pragma unroll
        for (int i = 0; i < 8; ++i) asm("" : "+v"(mask[i]));

        int cnt = 0;
        #pragma unroll
        for (int i = 0; i < 8; ++i) cnt += __builtin_popcount(mask[i]);
        int qf = -1;
        #pragma unroll
        for (int i = 0; i < 8; ++i) {
            if (qf < 0 && mask[i] != 0u)
                qf = (wave * 8 + i) * 32 + __builtin_ctz(mask[i]);
        }
        cntS[wave][lane] = cnt;
        qfS[wave][lane]  = qf;
        __syncthreads();

        int base = 0, tc = 0, gfirst = 0;
        #pragma unroll
        for (int w = 0; w < WAVES; ++w) {
            const int c = cntS[w][lane];
            const int f = qfS[w][lane];
            if (w < wave) base += c;
            gfirst = (tc == 0 && c > 0) ? f : gfirst;
            tc += c;
        }

        // sparse emit into LDS rows (disjoint slot ranges across waves)
        int slot = base;
        #pragma unroll
        for (int i = 0; i < 8; ++i) {
            unsigned m = mask[i];
            while (m != 0u && slot < K_OUT) {
                const int k = (int)__builtin_ctz(m);
                rows[lane * ROWPAD + slot] = (wave * 8 + i) * 32 + k;
                m &= m - 1u;
                ++slot;
            }
        }

        // pad: 8 slots per wave cover [0,64)
        #pragma unroll
        for (int s0 = 0; s0 < K_OUT / WAVES; ++s0) {
            const int s = wave * (K_OUT / WAVES) + s0;
            if (s >= tc) rows[lane * ROWPAD + s] = gfirst;
        }
        __syncthreads();   // also protects cntS rewrite next rep
    }

    // coalesced copy-out over the same region
    #pragma unroll
    for (int it = 0; it < (64 * K_OUT) / 512; ++it) {
        const int idx = it * 512 + tid;
        const int r = idx >> 6;
        const int c = idx & 63;
        reg[idx] = rows[r * ROWPAD + c];
    }
}

extern "C" void kernel_launch(void* const* d_in, const int* in_sizes, int n_in,
                              void* d_out, int out_size, void* d_ws, size_t ws_size,
                              hipStream_t stream) {
    const float* pcs = (const float*)d_in[0];
    int* out = (int*)d_out;
    bq_mask_kernel<<<2048, 256, 0, stream>>>(pcs, out);
    bq_emit_kernel<<<512, 512, 0, stream>>>(out);
}

// Round 20
// 78.295 us; speedup vs baseline: 2.5271x; 2.5271x over previous
//
#include <hip/hip_runtime.h>
#include <hip/hip_bf16.h>
#include <stdint.h>

// SelfBallPointQuery: B=16, C=3, N=2048, RADIUS^2=0.04, MAX_SAMPLES=64.
// R20: fused, occupancy-correct, minimal-instruction inner loop.
// R19 phase split measured: mask build 16.5us/pass @ 89% VALUBusy (32
// waves/CU) -- pure VALU-issue-bound at ~17 instr/point; emit only 2.3us.
// Fixes here:
//  - 1024-thr blocks x 16 waves, grid 512 -> 2 blocks/CU = 32 waves/CU
//    (the regime where stalls vanished). __launch_bounds__(1024,4) is a
//    minimum only -- no VGPR clamp (R11 lesson), natural ~40 VGPR lets HW
//    run 8 waves/SIMD.
//  - accumulate forced to 2 instr in ONE asm block (cmp+addc share vcc):
//    v_cmp_gt_f32 vcc, 0.04f, d2 ; v_addc_co_u32 m, vcc, m, m, vcc
//    -> ~12 VALU/point vs 17 (floor is 10 with exact numpy rounding; FMA &
//    MFMA d2 = |p|2-2pq+|q|2 are rounding-unsafe, ~100+ boundary flips).

#define B_DIM 16
#define N_PTS 2048
#define K_OUT 64
#define R2 0.04f
#define WAVES 16
#define BLOCK_T (WAVES * 64)            // 1024
#define JPW (N_PTS / WAVES)             // 128 points per wave
#define WPW (JPW / 32)                  // 4 mask words per lane
#define ROWPAD 65                       // LDS row stride

__global__ __launch_bounds__(BLOCK_T, 4) void ball_query_kernel(
    const float* __restrict__ pcs,   // (B, 3, N)
    int* __restrict__ out)           // (B, N, 64) int32
{
    __shared__ int rows[64 * ROWPAD];       // 16.64 KB
    __shared__ int cntS[WAVES][64];         // 4 KB
    __shared__ int qfS[WAVES][64];          // 4 KB

    const int b    = blockIdx.x >> 5;
    const int qg   = blockIdx.x & 31;
    const int tid  = threadIdx.x;
    const int wave = __builtin_amdgcn_readfirstlane(tid >> 6); // uniform
    const int lane = tid & 63;

    const float* __restrict__ sx = pcs + (size_t)b * 3 * N_PTS;
    const float* __restrict__ sy = sx + N_PTS;
    const float* __restrict__ sz = sy + N_PTS;

    const int qi = qg * 64 + lane;
    // pre-negated query coords (negation exact; squaring kills the sign)
    const float nx = -sx[qi], ny = -sy[qi], nz = -sz[qi];

    const int jbase = wave * JPW;
    int* const obase = out + (size_t)(b * N_PTS + qg * 64) * K_OUT;

    // ---- dense test phase: 4 words x 32 bits per lane ----
    unsigned mask[WPW];
    #pragma unroll
    for (int t = 0; t < WPW; ++t) {
        unsigned m = 0;
        #pragma unroll
        for (int k = 31; k >= 0; --k) {       // descending: bit k = point +k
            const int j = jbase + t * 32 + k; // wave-uniform -> s_load
            const float dx = __fadd_rn(sx[j], nx);   // == sx[j] - qx exactly
            const float dy = __fadd_rn(sy[j], ny);
            const float dz = __fadd_rn(sz[j], nz);
            const float d2 = __fadd_rn(__fadd_rn(__fmul_rn(dx, dx),
                                                 __fmul_rn(dy, dy)),
                                       __fmul_rn(dz, dz));
            // m = (m<<1) + (d2 < 0.04f) in exactly 2 VALU (vcc fused in one
            // block so scheduling can't split the def/use):
            asm("v_cmp_gt_f32 vcc, 0x3d23d70a, %1\n\t"
                "v_addc_co_u32 %0, vcc, %0, %0, vcc"
                : "+v"(m) : "v"(d2) : "vcc");
        }
        mask[t] = m;
    }

    // per-lane count + first hit within this wave's 128-pt window
    int cnt = 0;
    #pragma unroll
    for (int t = 0; t < WPW; ++t) cnt += __builtin_popcount(mask[t]);
    int qf = -1;
    #pragma unroll
    for (int t = 0; t < WPW; ++t) {
        if (qf < 0 && mask[t] != 0u)
            qf = jbase + t * 32 + __builtin_ctz(mask[t]);
    }
    cntS[wave][lane] = cnt;
    qfS[wave][lane]  = qf;
    __syncthreads();

    // prefix over earlier waves' counts for my query; global first hit
    int base = 0, tc = 0, gfirst = 0;
    #pragma unroll
    for (int w = 0; w < WAVES; ++w) {
        const int c = cntS[w][lane];
        const int f = qfS[w][lane];
        if (w < wave) base += c;
        gfirst = (tc == 0 && c > 0) ? f : gfirst;
        tc += c;
    }

    // ---- sparse emit into LDS rows (disjoint slot ranges across waves) ----
    int slot = base;
    #pragma unroll
    for (int t = 0; t < WPW; ++t) {
        unsigned m = mask[t];
        while (m != 0u && slot < K_OUT) {
            const int k = (int)__builtin_ctz(m);
            rows[lane * ROWPAD + slot] = jbase + t * 32 + k;
            m &= m - 1u;
            ++slot;
        }
    }

    // ---- pad: 4 slots per wave cover [0,64); fill gfirst where s >= tc ----
    #pragma unroll
    for (int s0 = 0; s0 < K_OUT / WAVES; ++s0) {
        const int s = wave * (K_OUT / WAVES) + s0;
        if (s >= tc) rows[lane * ROWPAD + s] = gfirst;
    }
    __syncthreads();

    // ---- coalesced copy-out: 64 rows x 64 ints ----
    #pragma unroll
    for (int it = 0; it < (64 * K_OUT) / BLOCK_T; ++it) {
        const int idx = it * BLOCK_T + tid;
        const int r = idx >> 6;
        const int c = idx & 63;
        obase[idx] = rows[r * ROWPAD + c];
    }
}

extern "C" void kernel_launch(void* const* d_in, const int* in_sizes, int n_in,
                              void* d_out, int out_size, void* d_ws, size_t ws_size,
                              hipStream_t stream) {
    const float* pcs = (const float*)d_in[0];
    int* out = (int*)d_out;
    const int grid = B_DIM * 32;     // 512 blocks = 2 blocks/CU x 16 waves
    ball_query_kernel<<<grid, BLOCK_T, 0, stream>>>(pcs, out);
}